// Round 3
// baseline (590.317 us; speedup 1.0000x reference)
//
#include <hip/hip_runtime.h>

// ApplyDF: deep-filter first NB_DF complex bins with 5-tap causal complex FIR
// over time; remaining bins pass through.
//
// spec : (B=32, 1, T=2000, F=481, 2) fp32
// coefs: (B=32, ORDER=5, T=2000, NB_DF=96, 2) fp32
// out  : same shape as spec
//
// v4: two stream-ordered launches.
//   A) full-array float4 copy spec->out  (known-good 6.3 TB/s pattern)
//   B) FIR overwrite of f<96 (coef stream float4-coalesced; fast path t>=4
//      has 15 unconditional independent loads)
// Rationale: v2 (deep loops) and v3 (flat, 15-wide MLP) both plateaued at
// ~190-210 us / ~2.8 TB/s with every measured pipe idle. Decompose into two
// streams with known ceilings to either hit ~150 us or prove the ceiling is
// environmental.

constexpr int ORDER = 5;
constexpr int NB_DF = 96;
constexpr int T_DIM = 2000;
constexpr int F_DIM = 481;
constexpr int B_DIM = 32;

constexpr int BLOCK = 256;

// ---------------- kernel A: full-array float4 copy ----------------
constexpr unsigned TOT_FLOATS = (unsigned)B_DIM * T_DIM * F_DIM * 2u; // 61,568,000
constexpr unsigned TOT4       = TOT_FLOATS / 4u;                      // 15,392,000
constexpr int      COPY_GRID  = 2048;
constexpr unsigned CS         = (unsigned)COPY_GRID * BLOCK;          // 524,288
constexpr unsigned FULL_ITERS = TOT4 / (4u * CS);                     // 7
constexpr unsigned FULL_END   = FULL_ITERS * 4u * CS;                 // 14,680,064

__global__ __launch_bounds__(BLOCK) void ApplyDF_copy4_kernel(
    const float4* __restrict__ in, float4* __restrict__ out)
{
    const unsigned gid = blockIdx.x * BLOCK + threadIdx.x;
    for (unsigned j = 0; j < FULL_ITERS; ++j) {
        const unsigned i0 = gid + j * 4u * CS;
        float4 v0 = in[i0];
        float4 v1 = in[i0 + CS];
        float4 v2 = in[i0 + 2u * CS];
        float4 v3 = in[i0 + 3u * CS];
        out[i0]           = v0;
        out[i0 + CS]      = v1;
        out[i0 + 2u * CS] = v2;
        out[i0 + 3u * CS] = v3;
    }
    // tail: 711,936 float4 (<= 2 grid-stride iterations)
    for (unsigned i = FULL_END + gid; i < TOT4; i += CS) out[i] = in[i];
}

// ---------------- kernel B: FIR on f<96 ----------------
constexpr int F4          = NB_DF / 2;                        // 48 bin-pairs
constexpr int FIR_THREADS = B_DIM * T_DIM * F4;               // 3,072,000
constexpr int FIR_BLOCKS  = FIR_THREADS / BLOCK;              // 12,000

__global__ __launch_bounds__(BLOCK, 4) void ApplyDF_29231547416739_kernel(
    const float2* __restrict__ spec,
    const float4* __restrict__ coefs4,   // coef rows are 768 B -> 16B-aligned
    float2* __restrict__ out)
{
    const int flat = blockIdx.x * BLOCK + threadIdx.x;
    const int col  = flat % F4;               // bins 2col, 2col+1
    const int rest = flat / F4;               // b*T_DIM + t
    const int b    = rest / T_DIM;
    const int t    = rest - b * T_DIM;

    const size_t rowbase = (size_t)b * T_DIM + t;

    float2 slo[ORDER], shi[ORDER];
    if (t >= ORDER - 1) {
        // fast path (99.8% of threads): 10 unconditional independent loads
        const float2* p0 = spec + (rowbase - (ORDER - 1)) * F_DIM + 2 * col;
#pragma unroll
        for (int n = 0; n < ORDER; ++n) {
            const float2* p = p0 + (size_t)n * F_DIM;
            slo[n] = p[0];
            shi[n] = p[1];
        }
    } else {
        // boundary path: clamp + select (zero-pad t<0)
#pragma unroll
        for (int n = 0; n < ORDER; ++n) {
            const int tt  = t + n - (ORDER - 1);
            const int ttc = tt >= 0 ? tt : 0;
            const float2* p = spec + ((size_t)b * T_DIM + ttc) * F_DIM + 2 * col;
            float2 lo = p[0];
            float2 hi = p[1];
            if (tt < 0) { lo = make_float2(0.f, 0.f); hi = make_float2(0.f, 0.f); }
            slo[n] = lo; shi[n] = hi;
        }
    }

    float4 c[ORDER];
#pragma unroll
    for (int n = 0; n < ORDER; ++n)
        c[n] = coefs4[(((size_t)b * ORDER + n) * T_DIM + t) * F4 + col];

    float4 acc = make_float4(0.f, 0.f, 0.f, 0.f);
#pragma unroll
    for (int n = 0; n < ORDER; ++n) {
        acc.x = fmaf(slo[n].x, c[n].x, fmaf(-slo[n].y, c[n].y, acc.x));
        acc.y = fmaf(slo[n].x, c[n].y, fmaf( slo[n].y, c[n].x, acc.y));
        acc.z = fmaf(shi[n].x, c[n].z, fmaf(-shi[n].y, c[n].w, acc.z));
        acc.w = fmaf(shi[n].x, c[n].w, fmaf( shi[n].y, c[n].z, acc.w));
    }

    float2* op = out + rowbase * F_DIM + 2 * col;
    op[0] = make_float2(acc.x, acc.y);
    op[1] = make_float2(acc.z, acc.w);
}

extern "C" void kernel_launch(void* const* d_in, const int* in_sizes, int n_in,
                              void* d_out, int out_size, void* d_ws, size_t ws_size,
                              hipStream_t stream) {
    const float2* spec   = (const float2*)d_in[0];
    const float4* coefs4 = (const float4*)d_in[1];
    float2* out = (float2*)d_out;

    // A: copy everything (perfectly aligned float4 stream)
    ApplyDF_copy4_kernel<<<dim3(COPY_GRID), dim3(BLOCK), 0, stream>>>(
        (const float4*)spec, (float4*)out);
    // B: overwrite f<96 with the FIR result (stream-ordered after A)
    ApplyDF_29231547416739_kernel<<<dim3(FIR_BLOCKS), dim3(BLOCK), 0, stream>>>(
        spec, coefs4, out);
}